// Round 6
// baseline (850.823 us; speedup 1.0000x reference)
//
#include <hip/hip_runtime.h>
#include <hip/hip_bf16.h>
#include <math.h>

#define D_MODEL 128
#define HW      1024
#define DEPTH   4
#define NIMG    128   // B*T
#define B_      8
#define T_      16
#define LN_EPSF 1e-5f

typedef short  s8  __attribute__((ext_vector_type(8)));
typedef ushort us8 __attribute__((ext_vector_type(8)));
typedef ushort us4 __attribute__((ext_vector_type(4)));
typedef float  f4  __attribute__((ext_vector_type(4)));

__device__ __forceinline__ float sig_(float x) { return 1.0f / (1.0f + __expf(-x)); }
__device__ __forceinline__ float tanh_(float x) { return 2.0f * sig_(2.0f * x) - 1.0f; }
__device__ __forceinline__ ushort f2b(float f) {
    __hip_bfloat16 h = __float2bfloat16(f);
    return *reinterpret_cast<ushort*>(&h);
}
__device__ __forceinline__ float b2f(ushort u) {
    __hip_bfloat16 h = *reinterpret_cast<__hip_bfloat16*>(&u);
    return __bfloat162float(h);
}

// ---------------------------------------------------------------------------
// wconv: fp32 -> bf16 weight pre-conversion
// ---------------------------------------------------------------------------
__global__ __launch_bounds__(256) void wconv_kernel(
    const float* __restrict__ src, ushort* __restrict__ dst, int n)
{
    int i = blockIdx.x * 256 + threadIdx.x;
    if (i < n) dst[i] = f2b(src[i]);
}

// ---------------------------------------------------------------------------
// Stage-2: 3-gate GEMM from LDS xs tile [q][d] ([64][136] bf16).
// Waves own 32-channel slices (all 3 gates) -> fuse nonlinearity in-register.
// mfma(A=W row e, B=xs col q): C col=q (lane&15), row=e -> us4 stores to
// global [n][q][d] layout (d-contiguous).
// ---------------------------------------------------------------------------
__device__ __forceinline__ void gates_from_lds(
    const ushort (*Xs)[136], const ushort* __restrict__ Wi,
    ushort* __restrict__ iu, ushort* __restrict__ og,
    size_t nbase, int q0, int tid)
{
    const int lane = tid & 63;
    const int wv   = tid >> 6;
    const int grp  = lane >> 4;
    const int lrow = lane & 15;
    const int ch0  = wv * 32;

    f4 aU[2][4], aI[2][4], aO[2][4];
    #pragma unroll
    for (int nt = 0; nt < 2; ++nt)
        #pragma unroll
        for (int qt = 0; qt < 4; ++qt) { aU[nt][qt] = (f4)0.f; aI[nt][qt] = (f4)0.f; aO[nt][qt] = (f4)0.f; }

    #pragma unroll
    for (int kk = 0; kk < 4; ++kk) {
        const int kb = kk * 32 + grp * 8;
        s8 xb[4], wu[2], wi[2], wo[2];
        #pragma unroll
        for (int qt = 0; qt < 4; ++qt)
            xb[qt] = *reinterpret_cast<const s8*>(&Xs[qt * 16 + lrow][kb]);
        #pragma unroll
        for (int nt = 0; nt < 2; ++nt) {
            const int e = ch0 + nt * 16 + lrow;
            wu[nt] = *reinterpret_cast<const s8*>(Wi + (size_t)e * D_MODEL + kb);
            wi[nt] = *reinterpret_cast<const s8*>(Wi + (size_t)(e + 128) * D_MODEL + kb);
            wo[nt] = *reinterpret_cast<const s8*>(Wi + (size_t)(e + 256) * D_MODEL + kb);
        }
        #pragma unroll
        for (int nt = 0; nt < 2; ++nt)
            #pragma unroll
            for (int qt = 0; qt < 4; ++qt) {
                aU[nt][qt] = __builtin_amdgcn_mfma_f32_16x16x32_bf16(wu[nt], xb[qt], aU[nt][qt], 0, 0, 0);
                aI[nt][qt] = __builtin_amdgcn_mfma_f32_16x16x32_bf16(wi[nt], xb[qt], aI[nt][qt], 0, 0, 0);
                aO[nt][qt] = __builtin_amdgcn_mfma_f32_16x16x32_bf16(wo[nt], xb[qt], aO[nt][qt], 0, 0, 0);
            }
    }

    #pragma unroll
    for (int nt = 0; nt < 2; ++nt)
        #pragma unroll
        for (int qt = 0; qt < 4; ++qt) {
            const int q = q0 + qt * 16 + lrow;
            const size_t off = nbase + (size_t)q * D_MODEL + ch0 + nt * 16 + grp * 4;
            us4 piu, pog;
            #pragma unroll
            for (int i = 0; i < 4; ++i) {
                piu[i] = f2b(sig_(aI[nt][qt][i]) * tanh_(aU[nt][qt][i]));
                pog[i] = f2b(sig_(aO[nt][qt][i]));
            }
            *reinterpret_cast<us4*>(iu + off) = piu;
            *reinterpret_cast<us4*>(og + off) = pog;
        }
}

// ---------------------------------------------------------------------------
// Stage-1 fragment loader: gated product G = S*og*scale, bf16 A-fragments
// straight from global [n][q][d] (wave owns q-subtile wv*16..+16).
// ---------------------------------------------------------------------------
__device__ __forceinline__ void stage1_gfrags(
    const ushort* __restrict__ S, const ushort* __restrict__ og,
    float scale, size_t nbase, int q0, int wv, int grp, int lrow, s8 g[4])
{
    const size_t rbase = nbase + (size_t)(q0 + wv * 16 + lrow) * D_MODEL + grp * 8;
    #pragma unroll
    for (int kk = 0; kk < 4; ++kk) {
        const size_t off = rbase + kk * 32;
        us8 sv = *reinterpret_cast<const us8*>(S + off);
        us8 ov = *reinterpret_cast<const us8*>(og + off);
        s8 gg;
        #pragma unroll
        for (int j = 0; j < 8; ++j)
            gg[j] = (short)f2b(b2f(sv[j]) * b2f(ov[j]) * scale);
        g[kk] = gg;
    }
}

// ---------------------------------------------------------------------------
// gates_f32: layer-0 spatial gates from fp32 tok [n][d][q]. LDS transpose
// staging, then 3-gate MFMA.
// ---------------------------------------------------------------------------
__global__ __launch_bounds__(256, 2) void gates_f32_kernel(
    const float* __restrict__ in, const ushort* __restrict__ Wi,
    ushort* __restrict__ iu, ushort* __restrict__ og)
{
    __shared__ ushort Xs[64][136];
    const int n   = blockIdx.x >> 4;
    const int q0  = (blockIdx.x & 15) << 6;
    const int tid = threadIdx.x;
    const size_t nbase = (size_t)n * (D_MODEL * HW);

    {
        const float* inb = in + nbase + q0;
        const int q   = tid & 63;
        const int dh0 = tid >> 6;
        for (int it = 0; it < 4; ++it) {
            const int dh = dh0 + it * 4;
            s8 pk;
            #pragma unroll
            for (int j = 0; j < 8; ++j)
                pk[j] = (short)f2b(inb[(size_t)(dh * 8 + j) * HW + q]);
            *reinterpret_cast<s8*>(&Xs[q][dh * 8]) = pk;
        }
    }
    __syncthreads();
    gates_from_lds(Xs, Wi, iu, og, nbase, q0, tid);
}

// ---------------------------------------------------------------------------
// fusedA: xs = Wo @ (og*S*scale) per tile (stage-1, wave-owns-q), xs kept in
// LDS, consumed by temporal 3-gate GEMM (stage-2). All activation I/O [n][q][d].
// In-place safe: all global reads precede __syncthreads, writes after.
// ---------------------------------------------------------------------------
__global__ __launch_bounds__(256, 2) void fusedA_kernel(
    const ushort* __restrict__ S, const ushort* __restrict__ og_in,
    const ushort* __restrict__ Wo, const ushort* __restrict__ Wi2,
    ushort* __restrict__ iu, ushort* __restrict__ og, float scale)
{
    __shared__ ushort Xs[64][136];
    const int n   = blockIdx.x >> 4;
    const int q0  = (blockIdx.x & 15) << 6;
    const int tid = threadIdx.x;
    const int lane = tid & 63, wv = tid >> 6, grp = lane >> 4, lrow = lane & 15;
    const size_t nbase = (size_t)n * (D_MODEL * HW);

    s8 g[4];
    stage1_gfrags(S, og_in, scale, nbase, q0, wv, grp, lrow, g);

    f4 C[8];
    #pragma unroll
    for (int et = 0; et < 8; ++et) C[et] = (f4)0.f;
    #pragma unroll
    for (int kk = 0; kk < 4; ++kk) {
        const int kb = kk * 32 + grp * 8;
        #pragma unroll
        for (int et = 0; et < 8; ++et) {
            s8 wf = *reinterpret_cast<const s8*>(Wo + (size_t)(et * 16 + lrow) * D_MODEL + kb);
            C[et] = __builtin_amdgcn_mfma_f32_16x16x32_bf16(g[kk], wf, C[et], 0, 0, 0);
        }
    }

    // xs tile -> LDS [q][e]
    #pragma unroll
    for (int et = 0; et < 8; ++et)
        #pragma unroll
        for (int i = 0; i < 4; ++i)
            Xs[wv * 16 + grp * 4 + i][et * 16 + lrow] = f2b(C[et][i]);
    __syncthreads();

    gates_from_lds(Xs, Wi2, iu, og, nbase, q0, tid);
}

// ---------------------------------------------------------------------------
// fusedB: X = resid + Wo @ (og*S). GATES: also feed bf16(X) into next layer's
// spatial gates. LN: instead of writing raw X, apply LayerNorm over D and
// write final output (wave holds all 128 e for its q's; shfl_xor reduce).
// resid/X are fp32 [n][d][q] (f4 loads/stores along q).
// ---------------------------------------------------------------------------
template <bool GATES, bool LN>
__global__ __launch_bounds__(256, 2) void fusedB_kernel(
    const ushort* __restrict__ S, const ushort* __restrict__ og_in,
    const ushort* __restrict__ Wo, const float* __restrict__ resid,
    float* __restrict__ X, const ushort* __restrict__ Wi2,
    ushort* __restrict__ iu, ushort* __restrict__ og,
    const float* __restrict__ lng, const float* __restrict__ lnb)
{
    __shared__ ushort Xs[64][136];
    const int n   = blockIdx.x >> 4;
    const int q0  = (blockIdx.x & 15) << 6;
    const int tid = threadIdx.x;
    const int lane = tid & 63, wv = tid >> 6, grp = lane >> 4, lrow = lane & 15;
    const size_t nbase = (size_t)n * (D_MODEL * HW);

    s8 g[4];
    stage1_gfrags(S, og_in, 1.0f, nbase, q0, wv, grp, lrow, g);

    f4 C[8];
    #pragma unroll
    for (int et = 0; et < 8; ++et) C[et] = (f4)0.f;
    #pragma unroll
    for (int kk = 0; kk < 4; ++kk) {
        const int kb = kk * 32 + grp * 8;
        #pragma unroll
        for (int et = 0; et < 8; ++et) {
            s8 wf = *reinterpret_cast<const s8*>(Wo + (size_t)(et * 16 + lrow) * D_MODEL + kb);
            C[et] = __builtin_amdgcn_mfma_f32_16x16x32_bf16(g[kk], wf, C[et], 0, 0, 0);
        }
    }

    const int qb = q0 + wv * 16 + grp * 4;   // 4 consecutive q (+i)

    if constexpr (LN) {
        float sum[4] = {0.f, 0.f, 0.f, 0.f}, sq[4] = {0.f, 0.f, 0.f, 0.f};
        #pragma unroll
        for (int et = 0; et < 8; ++et) {
            const int e = et * 16 + lrow;
            const size_t off = nbase + (size_t)e * HW + qb;
            f4 r = *reinterpret_cast<const f4*>(resid + off);
            #pragma unroll
            for (int i = 0; i < 4; ++i) {
                float v = C[et][i] + r[i];
                C[et][i] = v;
                sum[i] += v; sq[i] += v * v;
            }
        }
        #pragma unroll
        for (int m = 1; m <= 8; m <<= 1)
            #pragma unroll
            for (int i = 0; i < 4; ++i) {
                sum[i] += __shfl_xor(sum[i], m);
                sq[i]  += __shfl_xor(sq[i], m);
            }
        float mean[4], rstd[4];
        #pragma unroll
        for (int i = 0; i < 4; ++i) {
            mean[i] = sum[i] * (1.f / D_MODEL);
            float var = sq[i] * (1.f / D_MODEL) - mean[i] * mean[i];
            rstd[i] = rsqrtf(var + LN_EPSF);
        }
        #pragma unroll
        for (int et = 0; et < 8; ++et) {
            const int e = et * 16 + lrow;
            const float ge = lng[e], be = lnb[e];
            const size_t off = nbase + (size_t)e * HW + qb;
            f4 o;
            #pragma unroll
            for (int i = 0; i < 4; ++i)
                o[i] = (C[et][i] - mean[i]) * rstd[i] * ge + be;
            *reinterpret_cast<f4*>(X + off) = o;
        }
    } else {
        #pragma unroll
        for (int et = 0; et < 8; ++et) {
            const int e = et * 16 + lrow;
            const size_t off = nbase + (size_t)e * HW + qb;
            f4 r = *reinterpret_cast<const f4*>(resid + off);
            f4 v;
            #pragma unroll
            for (int i = 0; i < 4; ++i) v[i] = C[et][i] + r[i];
            *reinterpret_cast<f4*>(X + off) = v;
            if constexpr (GATES) {
                #pragma unroll
                for (int i = 0; i < 4; ++i)
                    Xs[wv * 16 + grp * 4 + i][e] = f2b(v[i]);
            }
        }
        if constexpr (GATES) {
            __syncthreads();
            gates_from_lds(Xs, Wi2, iu, og, nbase, q0, tid);
        }
    }
}

// ---------------------------------------------------------------------------
// rowscan (K1): per (n,i,d), lr+rl along j -> R buffer. d-coalesced.
// ---------------------------------------------------------------------------
__global__ __launch_bounds__(256) void rowscan_kernel(
    const ushort* __restrict__ iu, ushort* __restrict__ R,
    const float* __restrict__ Av)
{
    const int tid = blockIdx.x * 256 + threadIdx.x;   // 524288
    const int d = tid & 127;
    const int i = (tid >> 7) & 31;
    const int n = tid >> 12;
    const float a = fminf(__expf(Av[d]), 0.999f);
    const size_t base = (size_t)n * (D_MODEL * HW) + (size_t)(i * 32) * D_MODEL + d;

    float x[32], acc[32];
    #pragma unroll
    for (int j = 0; j < 32; ++j) x[j] = b2f(iu[base + (size_t)j * D_MODEL]);
    float s = 0.f;
    #pragma unroll
    for (int j = 0; j < 32; ++j) { s = fmaf(a, s, x[j]); acc[j] = s; }
    s = 0.f;
    #pragma unroll
    for (int j = 31; j >= 0; --j) { s = fmaf(a, s, x[j]); acc[j] += s; }
    #pragma unroll
    for (int j = 0; j < 32; ++j) R[base + (size_t)j * D_MODEL] = f2b(acc[j]);
}

// ---------------------------------------------------------------------------
// colscan+combine (K2): per (n,j,d), ud+du along i, add R, write S in place
// over iu (original x held in registers). d-coalesced.
// ---------------------------------------------------------------------------
__global__ __launch_bounds__(256) void colscan_kernel(
    ushort* __restrict__ buf, const ushort* __restrict__ R,
    const float* __restrict__ Av)
{
    const int tid = blockIdx.x * 256 + threadIdx.x;   // 524288
    const int d = tid & 127;
    const int j = (tid >> 7) & 31;
    const int n = tid >> 12;
    const float a = fminf(__expf(Av[d]), 0.999f);
    const size_t base = (size_t)n * (D_MODEL * HW) + (size_t)j * D_MODEL + d;
    const size_t istr = (size_t)32 * D_MODEL;

    float x[32], t[32];
    #pragma unroll
    for (int i = 0; i < 32; ++i) x[i] = b2f(buf[base + i * istr]);
    float s = 0.f;
    #pragma unroll
    for (int i = 0; i < 32; ++i) { s = fmaf(a, s, x[i]); t[i] = s; }
    s = 0.f;
    #pragma unroll
    for (int i = 31; i >= 0; --i) { s = fmaf(a, s, x[i]); t[i] += s; }
    #pragma unroll
    for (int i = 0; i < 32; ++i)
        buf[base + i * istr] = f2b(t[i] + b2f(R[base + i * istr]));
}

// ---------------------------------------------------------------------------
// tscan: causal scan over T in place (bf16 [n][q][d]), 8 channels/thread us8.
// ---------------------------------------------------------------------------
__global__ __launch_bounds__(256) void tscan_kernel(
    ushort* __restrict__ buf, const float* __restrict__ Av)
{
    const int tid = blockIdx.x * 256 + threadIdx.x;   // 131072
    const int dc = tid & 15;           // d-octet
    const int q  = (tid >> 4) & 1023;
    const int b  = tid >> 14;
    float aa[8], st[8];
    #pragma unroll
    for (int jj = 0; jj < 8; ++jj) {
        aa[jj] = fminf(__expf(Av[dc * 8 + jj]), 0.999f);
        st[jj] = 0.f;
    }
    #pragma unroll
    for (int t = 0; t < T_; ++t) {
        const size_t off = ((size_t)(b * T_ + t) * HW + q) * D_MODEL + dc * 8;
        us8 v = *reinterpret_cast<us8*>(buf + off);
        us8 w;
        #pragma unroll
        for (int jj = 0; jj < 8; ++jj) {
            st[jj] = fmaf(aa[jj], st[jj], b2f(v[jj]));
            w[jj] = f2b(st[jj]);
        }
        *reinterpret_cast<us8*>(buf + off) = w;
    }
}

// ---------------------------------------------------------------------------
extern "C" void kernel_launch(void* const* d_in, const int* in_sizes, int n_in,
                              void* d_out, int out_size, void* d_ws, size_t ws_size,
                              hipStream_t stream) {
    const float* tok   = (const float*)d_in[0];
    const float* s_inp = (const float*)d_in[1];
    const float* s_A   = (const float*)d_in[2];
    const float* s_out = (const float*)d_in[3];
    const float* t_inp = (const float*)d_in[4];
    const float* t_A   = (const float*)d_in[5];
    const float* t_out = (const float*)d_in[6];
    const float* ln_g  = (const float*)d_in[7];
    const float* ln_b  = (const float*)d_in[8];

    float*  X    = (float*)d_out;                    // residual stream fp32 [n][d][q]
    ushort* Abuf = (ushort*)d_ws;                    // 32MB bf16 [n][q][d] (iu / S)
    ushort* Bbuf = Abuf + (size_t)16777216;          // 32MB bf16 [n][q][d] (og)
    ushort* Cbuf = Bbuf + (size_t)16777216;          // 32MB bf16 [n][q][d] (rowscan R)
    ushort* Wbf  = Cbuf + (size_t)16777216;          // ~1MB bf16 weights
    ushort* sWiB = Wbf;                              // 4*49152
    ushort* sWoB = Wbf + 196608;                     // 4*16384
    ushort* tWiB = Wbf + 262144;
    ushort* tWoB = Wbf + 458752;

    const dim3 blk256(256);

    wconv_kernel<<<768, blk256, 0, stream>>>(s_inp, sWiB, 196608);
    wconv_kernel<<<256, blk256, 0, stream>>>(s_out, sWoB, 65536);
    wconv_kernel<<<768, blk256, 0, stream>>>(t_inp, tWiB, 196608);
    wconv_kernel<<<256, blk256, 0, stream>>>(t_out, tWoB, 65536);

    // layer-0 spatial gates from tok
    gates_f32_kernel<<<2048, blk256, 0, stream>>>(tok, sWiB, Abuf, Bbuf);

    for (int l = 0; l < DEPTH; ++l) {
        const float* xin = (l == 0) ? tok : X;

        rowscan_kernel<<<2048, blk256, 0, stream>>>(Abuf, Cbuf, s_A + (size_t)l * 128);
        colscan_kernel<<<2048, blk256, 0, stream>>>(Abuf, Cbuf, s_A + (size_t)l * 128);
        fusedA_kernel<<<2048, blk256, 0, stream>>>(
            Abuf, Bbuf, sWoB + (size_t)l * 16384, tWiB + (size_t)l * 49152,
            Abuf, Bbuf, 0.25f);
        tscan_kernel<<<512, blk256, 0, stream>>>(Abuf, t_A + (size_t)l * 128);

        if (l < DEPTH - 1) {
            fusedB_kernel<true, false><<<2048, blk256, 0, stream>>>(
                Abuf, Bbuf, tWoB + (size_t)l * 16384, xin, X,
                sWiB + (size_t)(l + 1) * 49152, Abuf, Bbuf, nullptr, nullptr);
        } else {
            fusedB_kernel<false, true><<<2048, blk256, 0, stream>>>(
                Abuf, Bbuf, tWoB + (size_t)l * 16384, xin, X,
                nullptr, nullptr, nullptr, ln_g, ln_b);
        }
    }
}

// Round 7
// 711.808 us; speedup vs baseline: 1.1953x; 1.1953x over previous
//
#include <hip/hip_runtime.h>
#include <hip/hip_bf16.h>
#include <math.h>

#define D_MODEL 128
#define HW      1024
#define DEPTH   4
#define NIMG    128   // B*T
#define B_      8
#define T_      16
#define LN_EPSF 1e-5f
#define TLN     131072   // elements per image (128*1024)
#define PS      1033     // scan LDS plane stride (dwords)

typedef short  s8  __attribute__((ext_vector_type(8)));
typedef ushort us8 __attribute__((ext_vector_type(8)));
typedef ushort us4 __attribute__((ext_vector_type(4)));
typedef float  f4  __attribute__((ext_vector_type(4)));

#define MFMA __builtin_amdgcn_mfma_f32_16x16x32_bf16

__device__ __forceinline__ float sig_(float x) { return 1.0f / (1.0f + __expf(-x)); }
__device__ __forceinline__ float tanh_(float x) { return 2.0f * sig_(2.0f * x) - 1.0f; }
__device__ __forceinline__ ushort f2b(float f) {
    __hip_bfloat16 h = __float2bfloat16(f);
    return *reinterpret_cast<ushort*>(&h);
}
__device__ __forceinline__ float b2f(ushort u) {
    __hip_bfloat16 h = *reinterpret_cast<__hip_bfloat16*>(&u);
    return __bfloat162float(h);
}

// ---------------------------------------------------------------------------
// wconv: fp32 -> bf16 weight pre-conversion
// ---------------------------------------------------------------------------
__global__ __launch_bounds__(256) void wconv_kernel(
    const float* __restrict__ src, ushort* __restrict__ dst, int n)
{
    int i = blockIdx.x * 256 + threadIdx.x;
    if (i < n) dst[i] = f2b(src[i]);
}

// ---------------------------------------------------------------------------
// 3-gate MFMA from LDS tile Xs[q][d]; stores iu/og to TILED layout:
// TL(d,q) = (d>>3)*8192 + q*8 + (d&7).  C: Adim(ch)=grp*4+i, Bdim(q)=lrow.
// us4 stores along ch within an octet -> 256B-contiguous runs along q.
// ---------------------------------------------------------------------------
__device__ __forceinline__ void gates_from_lds_TL(
    const ushort (*Xs)[136], const ushort* __restrict__ Wi,
    ushort* __restrict__ iu, ushort* __restrict__ og,
    size_t nbase, int q0, int tid)
{
    const int lane = tid & 63, wv = tid >> 6, grp = lane >> 4, lrow = lane & 15;
    const int ch0 = wv * 32;

    f4 aU[2][4], aI[2][4], aO[2][4];
    #pragma unroll
    for (int nt = 0; nt < 2; ++nt)
        #pragma unroll
        for (int qt = 0; qt < 4; ++qt) { aU[nt][qt] = (f4)0.f; aI[nt][qt] = (f4)0.f; aO[nt][qt] = (f4)0.f; }

    #pragma unroll
    for (int kk = 0; kk < 4; ++kk) {
        const int kb = kk * 32 + grp * 8;
        s8 xb[4], wu[2], wi[2], wo[2];
        #pragma unroll
        for (int qt = 0; qt < 4; ++qt)
            xb[qt] = *reinterpret_cast<const s8*>(&Xs[qt * 16 + lrow][kb]);
        #pragma unroll
        for (int nt = 0; nt < 2; ++nt) {
            const int e = ch0 + nt * 16 + lrow;
            wu[nt] = *reinterpret_cast<const s8*>(Wi + (size_t)e * D_MODEL + kb);
            wi[nt] = *reinterpret_cast<const s8*>(Wi + (size_t)(e + 128) * D_MODEL + kb);
            wo[nt] = *reinterpret_cast<const s8*>(Wi + (size_t)(e + 256) * D_MODEL + kb);
        }
        #pragma unroll
        for (int nt = 0; nt < 2; ++nt)
            #pragma unroll
            for (int qt = 0; qt < 4; ++qt) {
                aU[nt][qt] = MFMA(wu[nt], xb[qt], aU[nt][qt], 0, 0, 0);
                aI[nt][qt] = MFMA(wi[nt], xb[qt], aI[nt][qt], 0, 0, 0);
                aO[nt][qt] = MFMA(wo[nt], xb[qt], aO[nt][qt], 0, 0, 0);
            }
    }

    #pragma unroll
    for (int nt = 0; nt < 2; ++nt)
        #pragma unroll
        for (int qt = 0; qt < 4; ++qt) {
            const int ch = ch0 + nt * 16 + grp * 4;
            const int q  = q0 + qt * 16 + lrow;
            const size_t off = nbase + (size_t)(ch >> 3) * 8192 + (size_t)q * 8 + (ch & 7);
            us4 piu, pog;
            #pragma unroll
            for (int i = 0; i < 4; ++i) {
                piu[i] = f2b(sig_(aI[nt][qt][i]) * tanh_(aU[nt][qt][i]));
                pog[i] = f2b(sig_(aO[nt][qt][i]));
            }
            *reinterpret_cast<us4*>(iu + off) = piu;
            *reinterpret_cast<us4*>(og + off) = pog;
        }
}

// ---------------------------------------------------------------------------
// gates_f32: layer-0 spatial gates from fp32 tok [n][d][q].
// ---------------------------------------------------------------------------
__global__ __launch_bounds__(256, 2) void gates_f32_kernel(
    const float* __restrict__ in, const ushort* __restrict__ Wi,
    ushort* __restrict__ iu, ushort* __restrict__ og)
{
    __shared__ ushort Xs[64][136];
    const int n   = blockIdx.x >> 4;
    const int q0  = (blockIdx.x & 15) << 6;
    const int tid = threadIdx.x;
    const size_t nbase = (size_t)n * TLN;

    {
        const float* inb = in + nbase + q0;
        const int q = tid & 63, dh0 = tid >> 6;
        for (int it = 0; it < 4; ++it) {
            const int dh = dh0 + it * 4;
            s8 pk;
            #pragma unroll
            for (int j = 0; j < 8; ++j)
                pk[j] = (short)f2b(inb[(size_t)(dh * 8 + j) * HW + q]);
            *reinterpret_cast<s8*>(&Xs[q][dh * 8]) = pk;
        }
    }
    __syncthreads();
    gates_from_lds_TL(Xs, Wi, iu, og, nbase, q0, tid);
}

// ---------------------------------------------------------------------------
// scan2d: block=(n, d-octet). Coalesced us8 slab load -> swizzled fp32 LDS
// planes; row scans (lr+rl) -> R; col scans (ud+du) + R -> S; writes
// G = og * S * 0.25 (bf16, tiled). In-place over iu buffer.
// Swizzle: A(dc,pos) = dc*PS + (pos ^ (((pos>>5)&7)<<2))  [~2-way max]
// ---------------------------------------------------------------------------
__global__ __launch_bounds__(256, 2) void scan2d_kernel(
    ushort* bufG /* in: iu, out: G */, const ushort* __restrict__ og,
    const float* __restrict__ Av)
{
    __shared__ float P[8 * PS];
    __shared__ float R[8 * PS];
    const int n   = blockIdx.x >> 4;
    const int oct = blockIdx.x & 15;
    const int tid = threadIdx.x;
    const size_t base = (size_t)n * TLN + (size_t)oct * 8192;

    // phase 1: load slab [1024][8] -> P planes
    for (int it = 0; it < 4; ++it) {
        const int p  = it * 256 + tid;
        const int sw = p ^ (((p >> 5) & 7) << 2);
        us8 v = *reinterpret_cast<const us8*>(bufG + base + (size_t)p * 8);
        #pragma unroll
        for (int dc = 0; dc < 8; ++dc) P[dc * PS + sw] = b2f(v[dc]);
    }
    __syncthreads();

    const int dc  = tid & 7;
    const int row = tid >> 3;   // i for phase2, j for phase3 (0..31)
    const float a = fminf(__expf(Av[oct * 8 + dc]), 0.999f);

    // phase 2: row scans -> R
    {
        const int swb = (row * 32) ^ (((row & 7) << 2));
        float x[32], r[32];
        #pragma unroll
        for (int j = 0; j < 32; ++j) x[j] = P[dc * PS + (swb ^ j)];
        float s = 0.f;
        #pragma unroll
        for (int j = 0; j < 32; ++j) { s = fmaf(a, s, x[j]); r[j] = s; }
        s = 0.f;
        #pragma unroll
        for (int j = 31; j >= 0; --j) { s = fmaf(a, s, x[j]); r[j] += s; }
        #pragma unroll
        for (int j = 0; j < 32; ++j) R[dc * PS + (swb ^ j)] = r[j];
    }
    __syncthreads();

    // phase 3: col scans + add R -> P (final S)
    {
        float x[32], t[32];
        #pragma unroll
        for (int i = 0; i < 32; ++i) {
            const int p = i * 32 + row;
            x[i] = P[dc * PS + (p ^ ((i & 7) << 2))];
        }
        float s = 0.f;
        #pragma unroll
        for (int i = 0; i < 32; ++i) { s = fmaf(a, s, x[i]); t[i] = s; }
        s = 0.f;
        #pragma unroll
        for (int i = 31; i >= 0; --i) { s = fmaf(a, s, x[i]); t[i] += s; }
        #pragma unroll
        for (int i = 0; i < 32; ++i) {
            const int idx = dc * PS + ((i * 32 + row) ^ ((i & 7) << 2));
            P[idx] = t[i] + R[idx];
        }
    }
    __syncthreads();

    // phase 4: G = og * S * 0.25
    for (int it = 0; it < 4; ++it) {
        const int p  = it * 256 + tid;
        const int sw = p ^ (((p >> 5) & 7) << 2);
        us8 o = *reinterpret_cast<const us8*>(og + base + (size_t)p * 8);
        us8 w;
        #pragma unroll
        for (int d2 = 0; d2 < 8; ++d2)
            w[d2] = f2b(b2f(o[d2]) * P[d2 * PS + sw] * 0.25f);
        *reinterpret_cast<us8*>(bufG + base + (size_t)p * 8) = w;
    }
}

// ---------------------------------------------------------------------------
// MEGA temporal kernel: block=(b, 16-q tile), loops t=0..15 with SSM state in
// registers. Per t: stage G tile -> xs=WoS@G -> temporal gates(WiT) -> state
// -> G2 -> y=WoT@G2 -> X=resid+y -> [MODE 0: next-layer spatial gates(WiS2)
// -> iu/og | MODE 1: fused LayerNorm]. Ping-pong LDS, 4 barriers/t.
// ---------------------------------------------------------------------------
template <int MODE>   // 0 = mid layer, 1 = last layer (LN)
__global__ __launch_bounds__(256, 2) void mega_kernel(
    ushort* bufA /* in: G, out: next iu */, ushort* bufB /* out: next og */,
    const ushort* __restrict__ WoS, const ushort* __restrict__ WiT,
    const float* __restrict__ AvT,  const ushort* __restrict__ WoT,
    const float* __restrict__ resid, float* __restrict__ X,
    const ushort* __restrict__ WiS2,
    const float* __restrict__ lng, const float* __restrict__ lnb)
{
    __shared__ ushort Ls0[16][136];
    __shared__ ushort Ls1[16][136];
    __shared__ float  LnP[2][4][16];

    const int b    = blockIdx.x >> 6;
    const int qb0  = (blockIdx.x & 63) << 4;
    const int tid  = threadIdx.x;
    const int lane = tid & 63, wv = tid >> 6, grp = lane >> 4, lrow = lane & 15;
    const int c_oct = tid >> 4, c_qq = tid & 15;

    float aT[2];
    aT[0] = fminf(__expf(AvT[wv * 32 + lrow]), 0.999f);
    aT[1] = fminf(__expf(AvT[wv * 32 + 16 + lrow]), 0.999f);
    float ge[2], be[2];
    if constexpr (MODE == 1) {
        ge[0] = lng[wv * 32 + lrow];      be[0] = lnb[wv * 32 + lrow];
        ge[1] = lng[wv * 32 + 16 + lrow]; be[1] = lnb[wv * 32 + 16 + lrow];
    }

    f4 st[2]; st[0] = (f4)0.f; st[1] = (f4)0.f;

    us8 gpre = *reinterpret_cast<const us8*>(
        bufA + (size_t)(b * T_) * TLN + (size_t)c_oct * 8192 + (size_t)(qb0 + c_qq) * 8);

    for (int t = 0; t < T_; ++t) {
        const int n = b * T_ + t;
        const size_t nbase = (size_t)n * TLN;

        *reinterpret_cast<us8*>(&Ls0[c_qq][c_oct * 8]) = gpre;
        __syncthreads();                                             // S1
        if (t + 1 < T_)
            gpre = *reinterpret_cast<const us8*>(
                bufA + (size_t)(n + 1) * TLN + (size_t)c_oct * 8192 + (size_t)(qb0 + c_qq) * 8);

        // stage 1: xs = WoS @ G   (C: q=grp*4+i, e=wv*32+nt*16+lrow)
        s8 gf[4];
        #pragma unroll
        for (int kk = 0; kk < 4; ++kk)
            gf[kk] = *reinterpret_cast<const s8*>(&Ls0[lrow][kk * 32 + grp * 8]);
        f4 c1[2]; c1[0] = (f4)0.f; c1[1] = (f4)0.f;
        #pragma unroll
        for (int kk = 0; kk < 4; ++kk) {
            const int kb = kk * 32 + grp * 8;
            #pragma unroll
            for (int nt = 0; nt < 2; ++nt) {
                s8 wf = *reinterpret_cast<const s8*>(WoS + (size_t)(wv * 32 + nt * 16 + lrow) * D_MODEL + kb);
                c1[nt] = MFMA(gf[kk], wf, c1[nt], 0, 0, 0);
            }
        }
        #pragma unroll
        for (int nt = 0; nt < 2; ++nt)
            #pragma unroll
            for (int i = 0; i < 4; ++i)
                Ls1[grp * 4 + i][wv * 32 + nt * 16 + lrow] = f2b(c1[nt][i]);
        __syncthreads();                                             // S2

        // stage 2: temporal gates (C: q=grp*4+i, ch=wv*32+nt*16+lrow)
        s8 xf[4];
        #pragma unroll
        for (int kk = 0; kk < 4; ++kk)
            xf[kk] = *reinterpret_cast<const s8*>(&Ls1[lrow][kk * 32 + grp * 8]);
        f4 aU[2], aI[2], aO[2];
        #pragma unroll
        for (int nt = 0; nt < 2; ++nt) { aU[nt] = (f4)0.f; aI[nt] = (f4)0.f; aO[nt] = (f4)0.f; }
        #pragma unroll
        for (int kk = 0; kk < 4; ++kk) {
            const int kb = kk * 32 + grp * 8;
            #pragma unroll
            for (int nt = 0; nt < 2; ++nt) {
                const int e = wv * 32 + nt * 16 + lrow;
                s8 wu = *reinterpret_cast<const s8*>(WiT + (size_t)e * D_MODEL + kb);
                s8 wi = *reinterpret_cast<const s8*>(WiT + (size_t)(e + 128) * D_MODEL + kb);
                s8 wo = *reinterpret_cast<const s8*>(WiT + (size_t)(e + 256) * D_MODEL + kb);
                aU[nt] = MFMA(xf[kk], wu, aU[nt], 0, 0, 0);
                aI[nt] = MFMA(xf[kk], wi, aI[nt], 0, 0, 0);
                aO[nt] = MFMA(xf[kk], wo, aO[nt], 0, 0, 0);
            }
        }
        // state update + G2 -> Ls0
        #pragma unroll
        for (int nt = 0; nt < 2; ++nt)
            #pragma unroll
            for (int i = 0; i < 4; ++i) {
                const float iuv = sig_(aI[nt][i]) * tanh_(aU[nt][i]);
                st[nt][i] = fmaf(aT[nt], st[nt][i], iuv);
                Ls0[grp * 4 + i][wv * 32 + nt * 16 + lrow] = f2b(sig_(aO[nt][i]) * st[nt][i]);
            }
        __syncthreads();                                             // S3

        // stage 3: y = WoT @ G2 (C: q=grp*4+i, e=wv*32+nt*16+lrow)
        s8 g2f[4];
        #pragma unroll
        for (int kk = 0; kk < 4; ++kk)
            g2f[kk] = *reinterpret_cast<const s8*>(&Ls0[lrow][kk * 32 + grp * 8]);
        f4 c3[2]; c3[0] = (f4)0.f; c3[1] = (f4)0.f;
        #pragma unroll
        for (int kk = 0; kk < 4; ++kk) {
            const int kb = kk * 32 + grp * 8;
            #pragma unroll
            for (int nt = 0; nt < 2; ++nt) {
                s8 wf = *reinterpret_cast<const s8*>(WoT + (size_t)(wv * 32 + nt * 16 + lrow) * D_MODEL + kb);
                c3[nt] = MFMA(g2f[kk], wf, c3[nt], 0, 0, 0);
            }
        }
        // epilogue: v = c3 + resid (fp32 [n][d][q])
        f4 v[2];
        #pragma unroll
        for (int nt = 0; nt < 2; ++nt) {
            const int e = wv * 32 + nt * 16 + lrow;
            const size_t offX = nbase + (size_t)e * HW + (qb0 + grp * 4);
            f4 r = *reinterpret_cast<const f4*>(resid + offX);
            #pragma unroll
            for (int i = 0; i < 4; ++i) v[nt][i] = c3[nt][i] + r[i];
            if constexpr (MODE == 0)
                *reinterpret_cast<f4*>(X + offX) = v[nt];
        }

        if constexpr (MODE == 0) {
            // stage 4: next-layer spatial gates from Xb
            #pragma unroll
            for (int nt = 0; nt < 2; ++nt)
                #pragma unroll
                for (int i = 0; i < 4; ++i)
                    Ls1[grp * 4 + i][wv * 32 + nt * 16 + lrow] = f2b(v[nt][i]);
            __syncthreads();                                         // S4
            s8 xb2[4];
            #pragma unroll
            for (int kk = 0; kk < 4; ++kk)
                xb2[kk] = *reinterpret_cast<const s8*>(&Ls1[lrow][kk * 32 + grp * 8]);
            f4 bU[2], bI[2], bO[2];
            #pragma unroll
            for (int nt = 0; nt < 2; ++nt) { bU[nt] = (f4)0.f; bI[nt] = (f4)0.f; bO[nt] = (f4)0.f; }
            #pragma unroll
            for (int kk = 0; kk < 4; ++kk) {
                const int kb = kk * 32 + grp * 8;
                #pragma unroll
                for (int nt = 0; nt < 2; ++nt) {
                    const int ch = wv * 32 + nt * 16 + lrow;
                    s8 wu = *reinterpret_cast<const s8*>(WiS2 + (size_t)ch * D_MODEL + kb);
                    s8 wi = *reinterpret_cast<const s8*>(WiS2 + (size_t)(ch + 128) * D_MODEL + kb);
                    s8 wo = *reinterpret_cast<const s8*>(WiS2 + (size_t)(ch + 256) * D_MODEL + kb);
                    bU[nt] = MFMA(wu, xb2[kk], bU[nt], 0, 0, 0);
                    bI[nt] = MFMA(wi, xb2[kk], bI[nt], 0, 0, 0);
                    bO[nt] = MFMA(wo, xb2[kk], bO[nt], 0, 0, 0);
                }
            }
            // store iu/og (C: ch=grp*4+i within wave-tile, q=lrow)
            #pragma unroll
            for (int nt = 0; nt < 2; ++nt) {
                const int ch = wv * 32 + nt * 16 + grp * 4;
                const int q  = qb0 + lrow;
                const size_t off = nbase + (size_t)(ch >> 3) * 8192 + (size_t)q * 8 + (ch & 7);
                us4 piu, pog;
                #pragma unroll
                for (int i = 0; i < 4; ++i) {
                    piu[i] = f2b(sig_(bI[nt][i]) * tanh_(bU[nt][i]));
                    pog[i] = f2b(sig_(bO[nt][i]));
                }
                *reinterpret_cast<us4*>(bufA + off) = piu;
                *reinterpret_cast<us4*>(bufB + off) = pog;
            }
        } else {
            // fused LayerNorm over D: per-q sums across 4 waves
            float s4[4], q4[4];
            #pragma unroll
            for (int i = 0; i < 4; ++i) {
                s4[i] = v[0][i] + v[1][i];
                q4[i] = v[0][i] * v[0][i] + v[1][i] * v[1][i];
            }
            #pragma unroll
            for (int m = 1; m <= 8; m <<= 1)
                #pragma unroll
                for (int i = 0; i < 4; ++i) {
                    s4[i] += __shfl_xor(s4[i], m);
                    q4[i] += __shfl_xor(q4[i], m);
                }
            if (lrow == 0)
                #pragma unroll
                for (int i = 0; i < 4; ++i) {
                    LnP[0][wv][grp * 4 + i] = s4[i];
                    LnP[1][wv][grp * 4 + i] = q4[i];
                }
            __syncthreads();                                         // S4
            float mean[4], rstd[4];
            #pragma unroll
            for (int i = 0; i < 4; ++i) {
                float S = 0.f, Q = 0.f;
                #pragma unroll
                for (int w = 0; w < 4; ++w) { S += LnP[0][w][grp * 4 + i]; Q += LnP[1][w][grp * 4 + i]; }
                mean[i] = S * (1.f / D_MODEL);
                rstd[i] = rsqrtf(Q * (1.f / D_MODEL) - mean[i] * mean[i] + LN_EPSF);
            }
            #pragma unroll
            for (int nt = 0; nt < 2; ++nt) {
                const int e = wv * 32 + nt * 16 + lrow;
                const size_t offX = nbase + (size_t)e * HW + (qb0 + grp * 4);
                f4 o;
                #pragma unroll
                for (int i = 0; i < 4; ++i)
                    o[i] = (v[nt][i] - mean[i]) * rstd[i] * ge[nt] + be[nt];
                *reinterpret_cast<f4*>(X + offX) = o;
            }
        }
    }
}

// ---------------------------------------------------------------------------
extern "C" void kernel_launch(void* const* d_in, const int* in_sizes, int n_in,
                              void* d_out, int out_size, void* d_ws, size_t ws_size,
                              hipStream_t stream) {
    const float* tok   = (const float*)d_in[0];
    const float* s_inp = (const float*)d_in[1];
    const float* s_A   = (const float*)d_in[2];
    const float* s_out = (const float*)d_in[3];
    const float* t_inp = (const float*)d_in[4];
    const float* t_A   = (const float*)d_in[5];
    const float* t_out = (const float*)d_in[6];
    const float* ln_g  = (const float*)d_in[7];
    const float* ln_b  = (const float*)d_in[8];

    float*  X    = (float*)d_out;                    // residual stream fp32 [n][d][q]
    ushort* Abuf = (ushort*)d_ws;                    // 32MB bf16 tiled (iu / G)
    ushort* Bbuf = Abuf + (size_t)16777216;          // 32MB bf16 tiled (og)
    ushort* Wbf  = Bbuf + (size_t)16777216;          // ~1MB bf16 weights
    ushort* sWiB = Wbf;
    ushort* sWoB = Wbf + 196608;
    ushort* tWiB = Wbf + 262144;
    ushort* tWoB = Wbf + 458752;

    const dim3 blk256(256);

    wconv_kernel<<<768, blk256, 0, stream>>>(s_inp, sWiB, 196608);
    wconv_kernel<<<256, blk256, 0, stream>>>(s_out, sWoB, 65536);
    wconv_kernel<<<768, blk256, 0, stream>>>(t_inp, tWiB, 196608);
    wconv_kernel<<<256, blk256, 0, stream>>>(t_out, tWoB, 65536);

    // layer-0 spatial gates from tok
    gates_f32_kernel<<<2048, blk256, 0, stream>>>(tok, sWiB, Abuf, Bbuf);

    for (int l = 0; l < DEPTH; ++l) {
        const float* xin = (l == 0) ? tok : X;

        scan2d_kernel<<<2048, blk256, 0, stream>>>(Abuf, Bbuf, s_A + (size_t)l * 128);

        if (l < DEPTH - 1) {
            mega_kernel<0><<<512, blk256, 0, stream>>>(
                Abuf, Bbuf,
                sWoB + (size_t)l * 16384, tWiB + (size_t)l * 49152,
                t_A + (size_t)l * 128, tWoB + (size_t)l * 16384,
                xin, X, sWiB + (size_t)(l + 1) * 49152, nullptr, nullptr);
        } else {
            mega_kernel<1><<<512, blk256, 0, stream>>>(
                Abuf, Bbuf,
                sWoB + (size_t)l * 16384, tWiB + (size_t)l * 49152,
                t_A + (size_t)l * 128, tWoB + (size_t)l * 16384,
                xin, X, nullptr, ln_g, ln_b);
        }
    }
}